// Round 6
// baseline (626.900 us; speedup 1.0000x reference)
//
#include <hip/hip_runtime.h>
#include <math.h>

// ---------------------------------------------------------------------------
// CamembertLayer forward, bf16-MFMA, round 6.
// B=4 S=2048 H=1024 NH=16 HD=64 FF=4096
//
// Changes vs round 5:
//  - flash: 128 q-rows per block (wave owns 32 q = 2 q-groups). K/V LDS
//    fragment reads amortize over 2x q-columns (LDS-pipe was the binding
//    floor: 18 b128/tile/wave -> 20 per 2x work). Staging volume halves
//    (1024 blocks). Pt overlays the dead Qs region -> LDS 34.8KB = 4
//    blocks/CU, full residency. v_perm packed bf16 stores for P.
//  - QKV q/k epilogue: C-tile bounced through LDS -> coalesced 16B/lane
//    [bh][s][d] stores (was 2B scalar at 128B lane stride).
//
// Workspace (MB): unchanged from round 5.
// ---------------------------------------------------------------------------

#define H_   1024
#define NH_  16
#define HD_  64
#define FF_  4096
#define S_   2048
#define B_   4
#define BS_  (B_ * S_)

#define EPI_NONE 0
#define EPI_GELU 1
#define EPI_QKV3 2

typedef unsigned short ushort_t;
typedef short v8s __attribute__((ext_vector_type(8)));
typedef float v4f __attribute__((ext_vector_type(4)));
typedef unsigned int v2u __attribute__((ext_vector_type(2)));

__device__ __forceinline__ unsigned short f2bf(float f) {
    union { float f; unsigned int u; } v; v.f = f;
    unsigned int u = v.u;
    return (unsigned short)((u + 0x7fffu + ((u >> 16) & 1u)) >> 16);  // RNE
}
__device__ __forceinline__ float bf2f(unsigned short h) {
    union { unsigned int u; float f; } v; v.u = ((unsigned int)h) << 16;
    return v.f;
}
// pack two positive floats to bf16x2 (round-nearest, no tie-even): 3 VALU ops
__device__ __forceinline__ unsigned int pk2bf(float a, float b) {
    union { float f; unsigned int u; } ua, ub; ua.f = a; ub.f = b;
    return __builtin_amdgcn_perm(ub.u + 0x8000u, ua.u + 0x8000u, 0x07060302u);
}

typedef __attribute__((address_space(1))) void gvoid;
typedef __attribute__((address_space(3))) void lvoid;
__device__ __forceinline__ void async16(const void* g, void* l) {
    __builtin_amdgcn_global_load_lds((gvoid*)g, (lvoid*)l, 16, 0, 0);
}

// ---------------------------------------------------------------------------
__global__ __launch_bounds__(256)
void cast_bf16_kernel(const float* __restrict__ x, ushort_t* __restrict__ y)
{
    const size_t i = ((size_t)blockIdx.x * 256 + threadIdx.x) * 4;
    float4 v = *(const float4*)&x[i];
    ushort4 o;
    o.x = f2bf(v.x); o.y = f2bf(v.y); o.z = f2bf(v.z); o.w = f2bf(v.w);
    *(ushort4*)&y[i] = o;
}

// W fp32 [K][N] -> Wt bf16 [N][K].  grid(N/32, K/32).
__global__ __launch_bounds__(256)
void cast_transpose_kernel(const float* __restrict__ W, ushort_t* __restrict__ Wt,
                           int K, int N)
{
    __shared__ float tile[32][33];
    const int tid = threadIdx.x;
    const int n0 = blockIdx.x * 32, k0 = blockIdx.y * 32;
    const int r  = tid >> 3;
    const int c4 = (tid & 7) * 4;
    float4 v = *(const float4*)&W[(size_t)(k0 + r) * N + n0 + c4];
    tile[r][c4 + 0] = v.x; tile[r][c4 + 1] = v.y;
    tile[r][c4 + 2] = v.z; tile[r][c4 + 3] = v.w;
    __syncthreads();
    ushort4 o;
    o.x = f2bf(tile[c4 + 0][r]); o.y = f2bf(tile[c4 + 1][r]);
    o.z = f2bf(tile[c4 + 2][r]); o.w = f2bf(tile[c4 + 3][r]);
    *(ushort4*)&Wt[(size_t)(n0 + r) * K + k0 + c4] = o;
}

// bcat = [bq | bk | bv]
__global__ __launch_bounds__(256)
void concat3_kernel(const float* __restrict__ a, const float* __restrict__ b,
                    const float* __restrict__ c, float* __restrict__ o)
{
    const int i = blockIdx.x * 256 + threadIdx.x;   // 0..3071
    o[i] = (i < 1024) ? a[i] : (i < 2048) ? b[i - 1024] : c[i - 2048];
}

// ---------------------------------------------------------------------------
// bf16 MFMA GEMM: C = A[M,K] @ Bt[N,K]^T + bias.
// 128x128 tile, BK=32, 4 waves 2x2, 4x4 16x16x32 frags, async16 staging.
// EPI_QKV3 q/k blocks: epilogue bounced through LDS (coalesced stores).
// ---------------------------------------------------------------------------
template <int EPI>
__global__ __launch_bounds__(256)
void bgemm_kernel(const ushort_t* __restrict__ A, const ushort_t* __restrict__ Bt,
                  const float* __restrict__ bias, void* __restrict__ Cout,
                  int M, int N, int K)
{
    __shared__ ushort_t smem[17408];           // Atile|Btile (16KB) U Ct 128x136
    ushort_t* Atile = smem;                    // 128*32
    ushort_t* Btile = smem + 4096;             // 128*32

    const int tid  = threadIdx.x;
    const int wave = tid >> 6;
    const int lane = tid & 63;
    const int ml   = lane & 15;
    const int q8   = lane >> 4;
    const int wm   = wave >> 1, wn = wave & 1;
    const int blockM = blockIdx.y * 128;
    const int blockN = blockIdx.x * 128;

    v4f acc[4][4];
#pragma unroll
    for (int a = 0; a < 4; ++a)
#pragma unroll
        for (int b = 0; b < 4; ++b) acc[a][b] = (v4f)0.f;

    for (int kt = 0; kt < K; kt += 32) {
#pragma unroll
        for (int i = 0; i < 2; ++i) {
            const int chunk = (i * 4 + wave) * 64 + lane;   // 0..511
            const int row = chunk >> 2;
            const int kp  = chunk & 3;
            async16(A  + (size_t)(blockM + row) * K + kt + kp * 8, &Atile[chunk * 8]);
            async16(Bt + (size_t)(blockN + row) * K + kt + kp * 8, &Btile[chunk * 8]);
        }
        __syncthreads();

        v8s af[4], bfr[4];
#pragma unroll
        for (int a = 0; a < 4; ++a)
            af[a] = *(const v8s*)&Atile[(wm * 64 + a * 16 + ml) * 32 + q8 * 8];
#pragma unroll
        for (int b = 0; b < 4; ++b)
            bfr[b] = *(const v8s*)&Btile[(wn * 64 + b * 16 + ml) * 32 + q8 * 8];
#pragma unroll
        for (int a = 0; a < 4; ++a)
#pragma unroll
            for (int b = 0; b < 4; ++b)
                acc[a][b] = __builtin_amdgcn_mfma_f32_16x16x32_bf16(
                    af[a], bfr[b], acc[a][b], 0, 0, 0);
        __syncthreads();
    }

    // epilogue. C layout: col = lane&15, row = (lane>>4)*4 + r
    if (EPI == EPI_QKV3 && blockN < 2048) {
        // q/k: bounce through LDS, then coalesced [bh][s][d] row stores.
        // (loop ended with __syncthreads -> Atile/Btile dead)
#pragma unroll
        for (int a = 0; a < 4; ++a)
#pragma unroll
            for (int b = 0; b < 4; ++b) {
                const int n_loc = wn * 64 + b * 16 + ml;
                const float bn = bias[blockN + n_loc];
#pragma unroll
                for (int r = 0; r < 4; ++r)
                    smem[(wm * 64 + a * 16 + q8 * 4 + r) * 136 + n_loc] =
                        f2bf(acc[a][b][r] + bn);
            }
        __syncthreads();
        const int row  = tid >> 1, half = tid & 1;
        const int m    = blockM + row;
        const int hh   = ((blockN & 1023) >> 6) + half;
        ushort_t* gp = (ushort_t*)Cout + (blockN >= 1024 ? (size_t)BS_ * H_ : 0)
                     + (((size_t)((m >> 11) * NH_ + hh)) * S_ + (m & 2047)) * HD_;
        const ushort_t* lp = &smem[row * 136 + half * 64];
#pragma unroll
        for (int j = 0; j < 8; ++j)
            *(uint4*)&gp[j * 8] = *(const uint4*)&lp[j * 8];
        return;
    }

#pragma unroll
    for (int a = 0; a < 4; ++a) {
#pragma unroll
        for (int b = 0; b < 4; ++b) {
            const int n  = blockN + wn * 64 + b * 16 + ml;
            const float bn = bias[n];
            if (EPI == EPI_QKV3) {
                // v^T: [bh][d][s], 4 consecutive s -> packed ushort4
                const int nn = n & 1023;
                const int hh = nn >> 6, dd = nn & 63;
                ushort_t* base = (ushort_t*)Cout + (size_t)2 * BS_ * H_;
                const int m0 = blockM + wm * 64 + a * 16 + q8 * 4;
                ushort4 pk;
                pk.x = f2bf(acc[a][b][0] + bn);
                pk.y = f2bf(acc[a][b][1] + bn);
                pk.z = f2bf(acc[a][b][2] + bn);
                pk.w = f2bf(acc[a][b][3] + bn);
                *(ushort4*)&base[(((size_t)((m0 >> 11) * NH_ + hh)) * HD_ + dd) * S_
                                 + (m0 & 2047)] = pk;
            } else {
#pragma unroll
                for (int r = 0; r < 4; ++r) {
                    const int m = blockM + wm * 64 + a * 16 + q8 * 4 + r;
                    float v = acc[a][b][r] + bn;
                    if (EPI == EPI_GELU) {
                        v = v * 0.5f * (1.f + erff(v * 0.70710678118654752f));
                        v = fminf(fmaxf(v, -1e9f), 1e9f);
                        ((ushort_t*)Cout)[(size_t)m * N + n] = f2bf(v);
                    } else {
                        ((float*)Cout)[(size_t)m * N + n] = v;
                    }
                }
            }
        }
    }
}

// ---------------------------------------------------------------------------
// vsum[bh][d] = sum_s V^T[bh][d][s]  (contiguous row sums)
// ---------------------------------------------------------------------------
__global__ __launch_bounds__(256)
void vsum_kernel(const ushort_t* __restrict__ VT, float* __restrict__ vsum)
{
    const int bh   = blockIdx.x;
    const int tid  = threadIdx.x;
    const int d    = tid >> 2;
    const int part = tid & 3;
    const ushort_t* p = VT + (size_t)bh * HD_ * S_ + (size_t)d * S_ + part * 512;
    float acc = 0.f;
    for (int i = 0; i < 512; i += 4) {
        ushort4 u = *(const ushort4*)&p[i];
        acc += (bf2f(u.x) + bf2f(u.y)) + (bf2f(u.z) + bf2f(u.w));
    }
    acc += __shfl_xor(acc, 1);
    acc += __shfl_xor(acc, 2);
    if (part == 0) vsum[bh * HD_ + d] = acc;
}

// ---------------------------------------------------------------------------
// Flash attention, transposed-score, max-free softmax, 128-q blocks.
// grid(16 q-tiles, 64 bh), 4 waves; wave owns 32 q (2 groups of 16).
// K/V fragments amortize over 2 q-groups; Pt overlays dead Qs region.
// ---------------------------------------------------------------------------
__global__ __launch_bounds__(256, 4)
void flash_kernel(const ushort_t* __restrict__ Q, const ushort_t* __restrict__ Kg,
                  const ushort_t* __restrict__ VT, const float* __restrict__ vsum,
                  float* __restrict__ ctx)
{
    __shared__ ushort_t PtQ[128 * 72];   // Qs[128][64] (staging) U Pt[128][72]
    __shared__ ushort_t Ks[64 * 64];     // [key][d] swizzled
    __shared__ ushort_t Vs[64 * 64];     // [d][key] swizzled (from global V^T)

    const int bh   = blockIdx.y;
    const int q0   = blockIdx.x * 128;
    const int tid  = threadIdx.x;
    const int wave = tid >> 6;
    const int lane = tid & 63;
    const int ml   = lane & 15;
    const int q8   = lane >> 4;
    const int sw   = ml & 7;

    const ushort_t* Qp = Q  + (size_t)bh * S_ * HD_ + (size_t)q0 * HD_;
    const ushort_t* Kp = Kg + (size_t)bh * S_ * HD_;
    const ushort_t* Vp = VT + (size_t)bh * HD_ * S_;

    // stage Q tile [128][64] (swizzled) into PtQ with stride 64
#pragma unroll
    for (int i = 0; i < 4; ++i) {
        const int chunk = i * 256 + tid;     // 0..1023
        const int row = chunk >> 3, c = chunk & 7;
        async16(Qp + (size_t)row * HD_ + ((c ^ (row & 7)) * 8), &PtQ[chunk * 8]);
    }
    __syncthreads();   // Q staged

    // pull Q fragments to registers; PtQ region is then free for Pt
    v8s qf[2][2];
#pragma unroll
    for (int qg = 0; qg < 2; ++qg) {
        const int qrow = wave * 32 + qg * 16 + ml;     // qrow&7 == sw
        qf[qg][0] = *(const v8s*)&PtQ[qrow * 64 + ((q8 ^ sw) * 8)];
        qf[qg][1] = *(const v8s*)&PtQ[qrow * 64 + (((q8 + 4) ^ sw) * 8)];
    }

    const float C_ = 0.18033688011112042f;   // log2(e)/8
    float l_r[2] = {0.f, 0.f};
    v4f o[2][4];
#pragma unroll
    for (int qg = 0; qg < 2; ++qg)
#pragma unroll
        for (int g = 0; g < 4; ++g) o[qg][g] = (v4f)0.f;

    for (int t = 0; t < S_ / 64; ++t) {
        const int kv0 = t * 64;
        __syncthreads();   // prev-iter Ks/Vs reads done; t=0: qf loads done
#pragma unroll
        for (int i = 0; i < 2; ++i) {
            const int chunk = i * 256 + tid;
            const int row = chunk >> 3, c = chunk & 7;
            async16(Kp + (size_t)(kv0 + row) * HD_ + ((c ^ (row & 7)) * 8),
                    &Ks[chunk * 8]);
        }
#pragma unroll
        for (int i = 0; i < 2; ++i) {
            const int chunk = i * 256 + tid;
            const int row = chunk >> 3, c = chunk & 7;
            async16(Vp + (size_t)row * S_ + kv0 + ((c ^ (row & 7)) * 8),
                    &Vs[chunk * 8]);
        }
        __syncthreads();   // vmcnt drained: K/V tiles visible

        // S^T = K Q^T ; p = exp2(s*C_) ; pack to Pt (wave-private rows)
#pragma unroll
        for (int a = 0; a < 4; ++a) {
            const int krow = (a * 16 + ml) * 64;
            v8s kf0 = *(const v8s*)&Ks[krow + ((q8 ^ sw) * 8)];
            v8s kf1 = *(const v8s*)&Ks[krow + (((q8 + 4) ^ sw) * 8)];
#pragma unroll
            for (int qg = 0; qg < 2; ++qg) {
                v4f z = (v4f)0.f;
                z = __builtin_amdgcn_mfma_f32_16x16x32_bf16(kf0, qf[qg][0], z, 0, 0, 0);
                z = __builtin_amdgcn_mfma_f32_16x16x32_bf16(kf1, qf[qg][1], z, 0, 0, 0);
                const float p0 = __builtin_exp2f(z[0] * C_);
                const float p1 = __builtin_exp2f(z[1] * C_);
                const float p2 = __builtin_exp2f(z[2] * C_);
                const float p3 = __builtin_exp2f(z[3] * C_);
                l_r[qg] += (p0 + p1) + (p2 + p3);
                v2u pk;
                pk.x = pk2bf(p0, p1);
                pk.y = pk2bf(p2, p3);
                *(v2u*)&PtQ[(wave * 32 + qg * 16 + ml) * 72 + a * 16 + q8 * 4] = pk;
            }
        }

        // O^T += V^T P^T
        v8s pf[2][2];
#pragma unroll
        for (int qg = 0; qg < 2; ++qg) {
            const int prow = (wave * 32 + qg * 16 + ml) * 72;
            pf[qg][0] = *(const v8s*)&PtQ[prow + q8 * 8];
            pf[qg][1] = *(const v8s*)&PtQ[prow + 32 + q8 * 8];
        }
#pragma unroll
        for (int g = 0; g < 4; ++g) {
            const int vrow = (g * 16 + ml) * 64;
            v8s vf0 = *(const v8s*)&Vs[vrow + ((q8 ^ sw) * 8)];
            v8s vf1 = *(const v8s*)&Vs[vrow + (((q8 + 4) ^ sw) * 8)];
#pragma unroll
            for (int qg = 0; qg < 2; ++qg) {
                o[qg][g] = __builtin_amdgcn_mfma_f32_16x16x32_bf16(vf0, pf[qg][0],
                                                                   o[qg][g], 0, 0, 0);
                o[qg][g] = __builtin_amdgcn_mfma_f32_16x16x32_bf16(vf1, pf[qg][1],
                                                                   o[qg][g], 0, 0, 0);
            }
        }
    }

    // deferred l reduction + epilogue
    const int bb = bh >> 4, hh = bh & 15;
#pragma unroll
    for (int qg = 0; qg < 2; ++qg) {
        float l = l_r[qg];
        l += __shfl_xor(l, 16);
        l += __shfl_xor(l, 32);
        const float linv = 1.f / l;
        const int srow = q0 + wave * 32 + qg * 16 + ml;
        float* cp = ctx + ((size_t)(bb * S_ + srow)) * H_ + hh * HD_;
#pragma unroll
        for (int g = 0; g < 4; ++g) {
            float4 vs4 = *(const float4*)&vsum[bh * HD_ + g * 16 + q8 * 4];
            float4 ov;
            ov.x = o[qg][g][0] * linv + 1e-9f * vs4.x;
            ov.y = o[qg][g][1] * linv + 1e-9f * vs4.y;
            ov.z = o[qg][g][2] * linv + 1e-9f * vs4.z;
            ov.w = o[qg][g][3] * linv + 1e-9f * vs4.w;
            *(float4*)&cp[g * 16 + q8 * 4] = ov;
        }
    }
}

// ---------------------------------------------------------------------------
template <bool WB>
__global__ __launch_bounds__(256)
void add_ln_kernel(const float* __restrict__ A, const float* __restrict__ Bv,
                   const float* __restrict__ gamma, const float* __restrict__ beta,
                   float* __restrict__ out, ushort_t* __restrict__ outb)
{
    const int row = blockIdx.x;
    const int tid = threadIdx.x;
    const float* a = A  + (size_t)row * H_;
    const float* b = Bv + (size_t)row * H_;

    float4 av = *(const float4*)&a[tid * 4];
    float4 bv = *(const float4*)&b[tid * 4];
    float x[4] = { av.x + bv.x, av.y + bv.y, av.z + bv.z, av.w + bv.w };

    float s  = x[0] + x[1] + x[2] + x[3];
    float s2 = x[0]*x[0] + x[1]*x[1] + x[2]*x[2] + x[3]*x[3];
#pragma unroll
    for (int off = 1; off < 64; off <<= 1) {
        s  += __shfl_xor(s,  off);
        s2 += __shfl_xor(s2, off);
    }
    __shared__ float rs[8];
    const int wave = tid >> 6, lane = tid & 63;
    if (lane == 0) { rs[wave] = s; rs[4 + wave] = s2; }
    __syncthreads();
    const float sum  = rs[0] + rs[1] + rs[2] + rs[3];
    const float sum2 = rs[4] + rs[5] + rs[6] + rs[7];
    const float mu   = sum * (1.f / H_);
    const float var  = sum2 * (1.f / H_) - mu * mu;
    const float rstd = rsqrtf(var + 1e-12f);

    float4 gv = *(const float4*)&gamma[tid * 4];
    float4 be = *(const float4*)&beta[tid * 4];
    float4 ov;
    ov.x = (x[0] - mu) * rstd * gv.x + be.x;
    ov.y = (x[1] - mu) * rstd * gv.y + be.y;
    ov.z = (x[2] - mu) * rstd * gv.z + be.z;
    ov.w = (x[3] - mu) * rstd * gv.w + be.w;
    *(float4*)&out[(size_t)row * H_ + tid * 4] = ov;
    if (WB) {
        ushort4 ob;
        ob.x = f2bf(ov.x); ob.y = f2bf(ov.y); ob.z = f2bf(ov.z); ob.w = f2bf(ov.w);
        *(ushort4*)&outb[(size_t)row * H_ + tid * 4] = ob;
    }
}

// ---------------------------------------------------------------------------
extern "C" void kernel_launch(void* const* d_in, const int* in_sizes, int n_in,
                              void* d_out, int out_size, void* d_ws, size_t ws_size,
                              hipStream_t stream)
{
    const float* hidden = (const float*)d_in[0];
    const float* Wq     = (const float*)d_in[1];
    const float* bq     = (const float*)d_in[2];
    const float* Wk     = (const float*)d_in[3];
    const float* bk     = (const float*)d_in[4];
    const float* Wv     = (const float*)d_in[5];
    const float* bv     = (const float*)d_in[6];
    const float* ln1_g  = (const float*)d_in[7];
    const float* ln1_b  = (const float*)d_in[8];
    const float* W1     = (const float*)d_in[9];
    const float* b1     = (const float*)d_in[10];
    const float* W2     = (const float*)d_in[11];
    const float* b2     = (const float*)d_in[12];
    const float* ln2_g  = (const float*)d_in[13];
    const float* ln2_b  = (const float*)d_in[14];

    char* ws = (char*)d_ws;
    const size_t MB = 1024 * 1024;
    ushort_t* Xb    = (ushort_t*)(ws + 0);
    ushort_t* x1b   = (ushort_t*)(ws + 0);
    ushort_t* Wqt   = (ushort_t*)(ws + 16 * MB);   // Wqt|Wkt|Wvt contiguous
    ushort_t* Wkt   = (ushort_t*)(ws + 18 * MB);
    ushort_t* Wvt   = (ushort_t*)(ws + 20 * MB);
    ushort_t* W1t   = (ushort_t*)(ws + 16 * MB);
    ushort_t* W2t   = (ushort_t*)(ws + 24 * MB);
    ushort_t* q     = (ushort_t*)(ws + 32 * MB);   // q|k|vt contiguous
    ushort_t* k     = (ushort_t*)(ws + 48 * MB);
    ushort_t* vt    = (ushort_t*)(ws + 64 * MB);
    float*    ctx   = (float*)(ws + 80 * MB);
    ushort_t* inter = (ushort_t*)(ws + 32 * MB);
    float*    bcat  = (float*)(ws + 96 * MB);          // dead before out2
    float*    vsum  = (float*)(ws + 96 * MB + 16384);  // dead before out2
    float*    out2  = (float*)(ws + 96 * MB);
    float*    x1    = (float*)(ws + 128 * MB);
    float*    out   = (float*)d_out;

    const dim3 blk(256);

    // 0. casts / prep
    cast_bf16_kernel<<<dim3(BS_ * H_ / 1024), blk, 0, stream>>>(hidden, Xb);
    cast_transpose_kernel<<<dim3(32, 32),  blk, 0, stream>>>(Wq, Wqt, H_, H_);
    cast_transpose_kernel<<<dim3(32, 32),  blk, 0, stream>>>(Wk, Wkt, H_, H_);
    cast_transpose_kernel<<<dim3(32, 32),  blk, 0, stream>>>(Wv, Wvt, H_, H_);
    cast_transpose_kernel<<<dim3(32, 128), blk, 0, stream>>>(W2, W2t, FF_, H_);
    concat3_kernel<<<dim3(12), blk, 0, stream>>>(bq, bk, bv, bcat);

    // 1. fused QKV projection: [q | k | v^T]
    bgemm_kernel<EPI_QKV3><<<dim3(24, 64), blk, 0, stream>>>(
        Xb, Wqt, bcat, q, BS_, 3 * H_, H_);

    // 2. W1 transpose (Wqt region now free)
    cast_transpose_kernel<<<dim3(128, 32), blk, 0, stream>>>(W1, W1t, H_, FF_);

    // 3. V column sums (rows of V^T)
    vsum_kernel<<<dim3(B_ * NH_), blk, 0, stream>>>(vt, vsum);

    // 4. attention (128 q-rows per block)
    flash_kernel<<<dim3(S_ / 128, B_ * NH_), blk, 0, stream>>>(q, k, vt, vsum, ctx);

    // 5. x1 = LN1(hidden + ctx), + bf16 copy
    add_ln_kernel<true><<<dim3(BS_), blk, 0, stream>>>(hidden, ctx, ln1_g, ln1_b, x1, x1b);

    // 6. inter = gelu(x1 @ W1 + b1) bf16
    bgemm_kernel<EPI_GELU><<<dim3(32, 64), blk, 0, stream>>>(x1b, W1t, b1, inter, BS_, FF_, H_);

    // 7. out2 = inter @ W2 + b2 fp32
    bgemm_kernel<EPI_NONE><<<dim3(8, 64), blk, 0, stream>>>(inter, W2t, b2, out2, BS_, H_, FF_);

    // 8. d_out = LN2(out2 + x1)
    add_ln_kernel<false><<<dim3(BS_), blk, 0, stream>>>(out2, x1, ln2_g, ln2_b, out, nullptr);
}